// Round 6
// baseline (121.521 us; speedup 1.0000x reference)
//
#include <hip/hip_runtime.h>

#define NB 512
#define NT 256
#define NC 384
#define NH 64

typedef __bf16 bf16x8 __attribute__((ext_vector_type(8)));
typedef float f32x4 __attribute__((ext_vector_type(4)));
typedef float f32x16 __attribute__((ext_vector_type(16)));
typedef unsigned int u32;
typedef unsigned int u32x4 __attribute__((ext_vector_type(4)));
typedef unsigned short u16;

__device__ __forceinline__ u16 f2bf(float x) {
  u32 u = __builtin_bit_cast(u32, x);
  u32 r = (u + 0x7fffu + ((u >> 16) & 1u)) >> 16;  // RNE
  return (u16)r;
}
__device__ __forceinline__ u32 pkbf(float lo, float hi) {
  u32 r;
  asm("v_cvt_pk_bf16_f32 %0, %1, %2" : "=v"(r) : "v"(lo), "v"(hi));
  return r;
}
__device__ __forceinline__ void pl32swap(u32& a, u32& b) {
  asm volatile("v_permlane32_swap_b32 %0, %1" : "+v"(a), "+v"(b));
}
__device__ __forceinline__ void gload16(const void* g, void* l) {
  __builtin_amdgcn_global_load_lds(
      (const __attribute__((address_space(1))) void*)g,
      (__attribute__((address_space(3))) void*)l, 16, 0, 0);
}

// ---------------- kernel 0: W (3x[64][384] f32) -> combined [192][384] bf16 ----
__global__ __launch_bounds__(256) void wconv_k(const float* __restrict__ wk,
                                               const float* __restrict__ wq,
                                               const float* __restrict__ wv,
                                               u16* __restrict__ wb) {
  int i = blockIdx.x * 256 + threadIdx.x;
  if (i >= 192 * NC) return;
  int row = i / NC, col = i - row * NC;
  const float* s = (row < 64) ? wk : ((row < 128) ? wq : wv);
  wb[i] = f2bf(s[(row & 63) * NC + col]);
}

// ---------------- kernel 1: QKV GEMM, gload_lds-pipelined, N-split -----------
// C[m][n] = sum_c x[m][c]*W[n][c]. Block: 256 rows x 96 cols (half = bid&1).
// W-half resident in LDS (73.7 KB, R4's proven granule swizzle). x staged f32
// via global_load_lds ring (2 x 32 KB, BK=32), counted vmcnt(2) never drained
// in-loop (T3/T4): loads stay in flight across raw s_barriers.
__global__ __launch_bounds__(1024) void qkv_gemm(const float* __restrict__ x,
                                                 const u16* __restrict__ wb,
                                                 u16* __restrict__ kws,
                                                 u16* __restrict__ qws,
                                                 u16* __restrict__ vws) {
  __shared__ __align__(16) u16 Wl[96 * 384];    // 73728 B, row stride 768 B
  __shared__ __align__(16) float Xb[2 * 8192];  // 65536 B, 2 x [256 rows][32 f32]
  const int tid = threadIdx.x;
  const int lane = tid & 63, w = tid >> 6;
  const int l15 = lane & 15, lg = lane >> 4;
  const int bid = blockIdx.x;
  const int h = bid & 1;
  const size_t m0 = (size_t)(bid >> 1) * 256;

  // stage_x(kc): 2 gload_lds dwordx4 per thread; LDS dest linear (wave-uniform
  // base + lane*16); source granule pre-swizzled gp^(row&7) (rule #21).
  auto stage_x = [&](int kc) {
#pragma unroll
    for (int j = 0; j < 2; ++j) {
      int idx = tid + j * 1024;          // 0..2047
      int row = idx >> 3, gp = idx & 7;
      const float* src = x + (m0 + row) * NC + kc * 32 + ((gp ^ (row & 7)) << 2);
      float* dst = &Xb[(kc & 1) * 8192] + (size_t)((tid & 0xFFC0) + j * 1024) * 4;
      gload16(src, dst);
    }
  };

  // issue x chunks 0,1 first (longest pole), then W loads (L2-hot)
  stage_x(0);
  stage_x(1);
  {
    const u16* wsrc = wb + h * 96 * NC;
#pragma unroll
    for (int i = 0; i < 5; ++i) {
      int idx = tid + i * 1024;
      if (idx < 4608) {                  // 96 rows * 48 granules
        int nl = idx / 48, gs = idx - nl * 48;
        int gk = gs ^ (nl & 7);
        uint4 d = *(const uint4*)(wsrc + nl * NC + gk * 8);
        *(uint4*)((char*)Wl + nl * 768 + gs * 16) = d;
      }
    }
  }
  asm volatile("s_waitcnt lgkmcnt(0)" ::: "memory");  // W ds_writes done (their loads drained)
  asm volatile("s_waitcnt vmcnt(2)" ::: "memory");    // S0 landed; S1 still out
  __builtin_amdgcn_s_barrier();
  __builtin_amdgcn_sched_barrier(0);

  f32x4 acc[6];
#pragma unroll
  for (int nt = 0; nt < 6; ++nt) {
    f32x4 z = {};
    acc[nt] = z;
  }

  const int s7 = l15 & 7;
  const int arow = w * 16 + l15;  // (arow&7)==s7 since w*16 is a multiple of 16

#pragma unroll
  for (int t = 0; t < 12; ++t) {
    // ---- compute chunk t from buf[t&1] ----
    {
      const float* Xc = &Xb[(t & 1) * 8192] + arow * 32;
      float4 lo = *(const float4*)(Xc + (((2 * lg) ^ s7) << 2));
      float4 hi = *(const float4*)(Xc + (((2 * lg + 1) ^ s7) << 2));
      u32x4 av = {pkbf(lo.x, lo.y), pkbf(lo.z, lo.w), pkbf(hi.x, hi.y), pkbf(hi.z, hi.w)};
      bf16x8 af = __builtin_bit_cast(bf16x8, av);
#pragma unroll
      for (int nt = 0; nt < 6; ++nt) {
        int nl = nt * 16 + l15;
        bf16x8 b = *(const bf16x8*)((const char*)Wl + nl * 768 +
                                    (((t * 4 + lg) ^ s7) << 4));
        acc[nt] = __builtin_amdgcn_mfma_f32_16x16x32_bf16(af, b, acc[nt], 0, 0, 0);
      }
    }
    __builtin_amdgcn_s_barrier();        // all waves done reading buf[t&1]
    __builtin_amdgcn_sched_barrier(0);
    if (t < 10) stage_x(t + 2);          // overwrite buf[t&1] with chunk t+2
    if (t < 11) {
      if (t < 10) asm volatile("s_waitcnt vmcnt(2)" ::: "memory");  // S_{t+1} landed
      else        asm volatile("s_waitcnt vmcnt(0)" ::: "memory");  // last: S_11
      __builtin_amdgcn_s_barrier();      // buf[(t+1)&1] ready for everyone
      __builtin_amdgcn_sched_barrier(0);
    }
  }

  // ---- epilogue: acc -> LDS bounce (reuse Xb) -> full-line stores ----
  u16* Cb = (u16*)Xb;                    // [256][96] bf16 = 48 KB
#pragma unroll
  for (int nt = 0; nt < 6; ++nt) {
#pragma unroll
    for (int r = 0; r < 4; ++r) {
      int mloc = w * 16 + lg * 4 + r;    // D row = (lane>>4)*4 + reg
      Cb[mloc * 96 + nt * 16 + l15] = f2bf(acc[nt][r]);
    }
  }
  asm volatile("s_waitcnt lgkmcnt(0)" ::: "memory");
  __builtin_amdgcn_s_barrier();
  __builtin_amdgcn_sched_barrier(0);
  {
    u16* const bases[3] = {kws, qws, vws};
#pragma unroll
    for (int i = 0; i < 3; ++i) {
      int idx = tid + i * 1024;          // 0..3071 = 256 rows x 12 segs
      int row = idx / 12, seg = idx - row * 12;
      int n0 = h * 96 + seg * 8;
      uint4 d = *(const uint4*)(Cb + row * 96 + seg * 8);
      *(uint4*)(bases[n0 >> 6] + (m0 + row) * NH + (n0 & 63)) = d;
    }
  }
}

// ---------------- kernel 2: fused causal attention per batch -----------------
__global__ __launch_bounds__(256) void attn_k(const u16* __restrict__ kws,
                                              const u16* __restrict__ qws,
                                              const u16* __restrict__ vws,
                                              float* __restrict__ out) {
  __shared__ u16 Klds[256 * 64];      // 32 KB, [s][h], swizzled
  __shared__ u16 VT[64 * 256];        // 32 KB, [h][s], swizzled
  const int b = blockIdx.x;
  const int tid = threadIdx.x, lane = tid & 63, w = tid >> 6;
  const int gl = lane >> 5, l31 = lane & 31;
  const u16* kb = kws + (size_t)b * NT * NH;
  const u16* qb = qws + (size_t)b * NT * NH;
  const u16* vb = vws + (size_t)b * NT * NH;

#pragma unroll
  for (int p = 0; p < 8; ++p) {
    int u = tid + p * 256;
    int row = u >> 3, c16 = u & 7;
    uint4 d = *(const uint4*)(kb + row * 64 + c16 * 8);
    *(uint4*)((char*)Klds + row * 128 + ((c16 * 16) ^ ((row & 7) << 4))) = d;
  }
#pragma unroll
  for (int p = 0; p < 8; ++p) {
    int u = tid + p * 256;
    int s = u >> 3, h0 = (u & 7) * 8;
    uint4 d = *(const uint4*)(vb + s * 64 + h0);
    u32 ww[4] = {d.x, d.y, d.z, d.w};
#pragma unroll
    for (int j = 0; j < 4; ++j) {
      int h = h0 + 2 * j;
      *(u16*)((char*)VT + h * 512 + ((s * 2) ^ ((h & 7) << 4))) = (u16)(ww[j] & 0xffffu);
      *(u16*)((char*)VT + (h + 1) * 512 + ((s * 2) ^ (((h + 1) & 7) << 4))) = (u16)(ww[j] >> 16);
    }
  }
  __syncthreads();

  const float cexp = 0.05103103630798287f * 1.4426950408889634f;  // C^-0.5 * log2(e)

#pragma unroll
  for (int pass = 0; pass < 2; ++pass) {
    const int qt = (pass == 0) ? w : 7 - w;
    const int t0 = qt * 32;

    bf16x8 bq[4];
#pragma unroll
    for (int kk = 0; kk < 4; ++kk)
      bq[kk] = *(const bf16x8*)(qb + (t0 + l31) * NH + kk * 16 + gl * 8);

    f32x16 sf[8];
#pragma unroll
    for (int f = 0; f < 8; ++f) {
      if (f <= qt) {
        f32x16 z = {};
        sf[f] = z;
#pragma unroll
        for (int kk = 0; kk < 4; ++kk) {
          int arow = f * 32 + l31;
          bf16x8 a = *(const bf16x8*)((const char*)Klds + arow * 128 +
                                      ((kk * 32 + gl * 16) ^ ((arow & 7) << 4)));
          sf[f] = __builtin_amdgcn_mfma_f32_32x32x16_bf16(a, bq[kk], sf[f], 0, 0, 0);
        }
      }
    }

    float mmax = -INFINITY;
#pragma unroll
    for (int f = 0; f < 8; ++f) {
      if (f < qt) {
#pragma unroll
        for (int r = 0; r < 16; ++r) mmax = fmaxf(mmax, sf[f][r]);
      } else if (f == qt) {
#pragma unroll
        for (int r = 0; r < 16; ++r) {
          int sloc = (r & 3) + 8 * (r >> 2) + 4 * gl;
          float v = (sloc <= l31) ? sf[f][r] : -INFINITY;
          mmax = fmaxf(mmax, v);
        }
      }
    }
    mmax = fmaxf(mmax, __shfl_xor(mmax, 32));

    float lsum = 0.0f;
#pragma unroll
    for (int f = 0; f < 8; ++f) {
      if (f <= qt) {
#pragma unroll
        for (int r = 0; r < 16; ++r) {
          float e = exp2f((sf[f][r] - mmax) * cexp);
          if (f == qt) {
            int sloc = (r & 3) + 8 * (r >> 2) + 4 * gl;
            e = (sloc <= l31) ? e : 0.0f;
          }
          sf[f][r] = e;
          lsum += e;
        }
      }
    }
    lsum += __shfl_xor(lsum, 32);

    f32x16 ao0 = {}, ao1 = {};
#pragma unroll
    for (int f = 0; f < 8; ++f) {
      if (f <= qt) {
        u32 a0 = pkbf(sf[f][0], sf[f][1]);
        u32 a1 = pkbf(sf[f][2], sf[f][3]);
        u32 b0 = pkbf(sf[f][4], sf[f][5]);
        u32 b1 = pkbf(sf[f][6], sf[f][7]);
        pl32swap(a0, b0);
        pl32swap(a1, b1);
        u32x4 te = {a0, a1, b0, b1};
        bf16x8 bpe = __builtin_bit_cast(bf16x8, te);
        u32 c0 = pkbf(sf[f][8], sf[f][9]);
        u32 c1 = pkbf(sf[f][10], sf[f][11]);
        u32 d0 = pkbf(sf[f][12], sf[f][13]);
        u32 d1 = pkbf(sf[f][14], sf[f][15]);
        pl32swap(c0, d0);
        pl32swap(c1, d1);
        u32x4 to = {c0, c1, d0, d1};
        bf16x8 bpo = __builtin_bit_cast(bf16x8, to);

        int se = (f * 32 + gl * 8) * 2;
        int so = se + 32;
        bf16x8 av0e = *(const bf16x8*)((char*)VT + l31 * 512 + (se ^ ((l31 & 7) << 4)));
        bf16x8 av1e = *(const bf16x8*)((char*)VT + (32 + l31) * 512 + (se ^ ((l31 & 7) << 4)));
        ao0 = __builtin_amdgcn_mfma_f32_32x32x16_bf16(av0e, bpe, ao0, 0, 0, 0);
        ao1 = __builtin_amdgcn_mfma_f32_32x32x16_bf16(av1e, bpe, ao1, 0, 0, 0);
        bf16x8 av0o = *(const bf16x8*)((char*)VT + l31 * 512 + (so ^ ((l31 & 7) << 4)));
        bf16x8 av1o = *(const bf16x8*)((char*)VT + (32 + l31) * 512 + (so ^ ((l31 & 7) << 4)));
        ao0 = __builtin_amdgcn_mfma_f32_32x32x16_bf16(av0o, bpo, ao0, 0, 0, 0);
        ao1 = __builtin_amdgcn_mfma_f32_32x32x16_bf16(av1o, bpo, ao1, 0, 0, 0);
      }
    }

    float rl = 1.0f / lsum;
    float* ob = out + ((size_t)b * NT + t0 + l31) * NH;
#pragma unroll
    for (int g = 0; g < 4; ++g) {
      float4 v0 = make_float4(ao0[4 * g + 0] * rl, ao0[4 * g + 1] * rl,
                              ao0[4 * g + 2] * rl, ao0[4 * g + 3] * rl);
      float4 v1 = make_float4(ao1[4 * g + 0] * rl, ao1[4 * g + 1] * rl,
                              ao1[4 * g + 2] * rl, ao1[4 * g + 3] * rl);
      *(float4*)(ob + 8 * g + 4 * gl) = v0;
      *(float4*)(ob + 32 + 8 * g + 4 * gl) = v1;
    }
  }
}

// ---------------- launch -----------------------------------------------------
extern "C" void kernel_launch(void* const* d_in, const int* in_sizes, int n_in,
                              void* d_out, int out_size, void* d_ws, size_t ws_size,
                              hipStream_t stream) {
  const float* x = (const float*)d_in[0];
  const float* wk = (const float*)d_in[1];
  const float* wq = (const float*)d_in[2];
  const float* wv = (const float*)d_in[3];
  float* out = (float*)d_out;

  char* ws = (char*)d_ws;
  u16* wb = (u16*)ws;                                   // 147456 B
  u16* kws = (u16*)(ws + (1 << 20));                    // 16 MB each
  u16* qws = kws + (size_t)NB * NT * NH;
  u16* vws = qws + (size_t)NB * NT * NH;

  wconv_k<<<288, 256, 0, stream>>>(wk, wq, wv, wb);
  qkv_gemm<<<1024, 1024, 0, stream>>>(x, wb, kws, qws, vws);
  attn_k<<<512, 256, 0, stream>>>(kws, qws, vws, out);
}

// Round 7
// 119.943 us; speedup vs baseline: 1.0132x; 1.0132x over previous
//
#include <hip/hip_runtime.h>

#define NB 512
#define NT 256
#define NC 384
#define NH 64

typedef __bf16 bf16x8 __attribute__((ext_vector_type(8)));
typedef float f32x4 __attribute__((ext_vector_type(4)));
typedef float f32x16 __attribute__((ext_vector_type(16)));
typedef unsigned int u32;
typedef unsigned int u32x4 __attribute__((ext_vector_type(4)));
typedef unsigned short u16;

__device__ __forceinline__ u16 f2bf(float x) {
  u32 u = __builtin_bit_cast(u32, x);
  u32 r = (u + 0x7fffu + ((u >> 16) & 1u)) >> 16;  // RNE
  return (u16)r;
}
__device__ __forceinline__ u32 pkbf(float lo, float hi) {
  u32 r;
  asm("v_cvt_pk_bf16_f32 %0, %1, %2" : "=v"(r) : "v"(lo), "v"(hi));
  return r;
}
__device__ __forceinline__ void pl32swap(u32& a, u32& b) {
  asm volatile("v_permlane32_swap_b32 %0, %1" : "+v"(a), "+v"(b));
}

// ---------------- kernel 0: W (3x[64][384] f32) -> combined [192][384] bf16 ----
__global__ __launch_bounds__(256) void wconv_k(const float* __restrict__ wk,
                                               const float* __restrict__ wq,
                                               const float* __restrict__ wv,
                                               u16* __restrict__ wb) {
  int i = blockIdx.x * 256 + threadIdx.x;
  if (i >= 192 * NC) return;
  int row = i / NC, col = i - row * NC;
  const float* s = (row < 64) ? wk : ((row < 128) ? wq : wv);
  wb[i] = f2bf(s[(row & 63) * NC + col]);
}

// ---------------- kernel 1: QKV GEMM — R4 skeleton + K-split W + B-frag reuse
// C[m][n] = sum_c x[m][c]*W[n][c];  M=131072, K=384, N=192.
// Block: 512 thr = 8 waves (4 row-grp x 2 col-grp) = 128 rows x 192 cols.
// Wave: 32 rows x 96 cols; per K=32 step: 6 ds_read_b128 (16-row frags, 2-way
// free aliasing) feed 12 mfma_16x16x32. W K-half resident in LDS (73.7 KB ->
// 2 blocks/CU, 16 waves/CU); mid-kernel reload of half 1 (L2-hot). x streamed
// global->reg (depth-2 ring), read exactly once. No in-loop barriers.
__global__ __launch_bounds__(512, 4) void qkv_gemm(const float* __restrict__ x,
                                                   const u16* __restrict__ wb,
                                                   u16* __restrict__ kws,
                                                   u16* __restrict__ qws,
                                                   u16* __restrict__ vws) {
  __shared__ __align__(16) u16 Wl[192 * 192];  // 73728 B; [nrow][klocal]; stride 384 B
  const int tid = threadIdx.x;
  const int lane = tid & 63, w = tid >> 6;
  const int l15 = lane & 15, lg = (lane >> 4) & 3;
  const int rg = w >> 1, cg = w & 1;
  const size_t m0 = (size_t)blockIdx.x * 128;

  const float* xp0 = x + (m0 + (size_t)(rg * 32 + l15)) * NC + lg * 8;
  const float* xp1 = xp0 + 16 * NC;

  // depth-2 prefetch ring: slot s holds step-u (u%2==s) A-data for both row-tiles
  float4 pa[2][2], pb[2][2];
#pragma unroll
  for (int s = 0; s < 2; ++s) {
    pa[s][0] = *(const float4*)(xp0 + s * 32);
    pa[s][1] = *(const float4*)(xp0 + s * 32 + 4);
    pb[s][0] = *(const float4*)(xp1 + s * 32);
    pb[s][1] = *(const float4*)(xp1 + s * 32 + 4);
  }

  // stage W K-half kh: Wl[nrow][gs] = wb[nrow][kh*192 + (gs^(nrow&7))*8 ..]
  auto stage_w = [&](int kh) {
#pragma unroll
    for (int i = 0; i < 9; ++i) {
      int idx = tid + i * 512;           // 0..4607 = 192 rows x 24 granules
      int nrow = idx / 24, gs = idx - nrow * 24;
      int gk = gs ^ (nrow & 7);          // stays within 0..23 (3-bit XOR)
      uint4 d = *(const uint4*)(wb + nrow * NC + kh * 192 + gk * 8);
      *(uint4*)((char*)Wl + nrow * 384 + gs * 16) = d;
    }
  };

  stage_w(0);
  __syncthreads();

  f32x4 acc[2][6];
#pragma unroll
  for (int rt = 0; rt < 2; ++rt)
#pragma unroll
    for (int nt = 0; nt < 6; ++nt) {
      f32x4 z = {};
      acc[rt][nt] = z;
    }

#pragma unroll
  for (int u = 0; u < 12; ++u) {
    if (u == 6) {  // swap to W K-half 1
      __syncthreads();
      stage_w(1);
      __syncthreads();
    }
    const int st = u & 1;
    const int s6 = (u < 6) ? u : (u - 6);
    u32x4 a0v = {pkbf(pa[st][0].x, pa[st][0].y), pkbf(pa[st][0].z, pa[st][0].w),
                 pkbf(pa[st][1].x, pa[st][1].y), pkbf(pa[st][1].z, pa[st][1].w)};
    bf16x8 af0 = __builtin_bit_cast(bf16x8, a0v);
    u32x4 a1v = {pkbf(pb[st][0].x, pb[st][0].y), pkbf(pb[st][0].z, pb[st][0].w),
                 pkbf(pb[st][1].x, pb[st][1].y), pkbf(pb[st][1].z, pb[st][1].w)};
    bf16x8 af1 = __builtin_bit_cast(bf16x8, a1v);
    if (u < 10) {  // refill slot with step u+2
      pa[st][0] = *(const float4*)(xp0 + (u + 2) * 32);
      pa[st][1] = *(const float4*)(xp0 + (u + 2) * 32 + 4);
      pb[st][0] = *(const float4*)(xp1 + (u + 2) * 32);
      pb[st][1] = *(const float4*)(xp1 + (u + 2) * 32 + 4);
    }
#pragma unroll
    for (int nt = 0; nt < 6; ++nt) {
      int nl = cg * 96 + nt * 16 + l15;
      bf16x8 b = *(const bf16x8*)((const char*)Wl + nl * 384 +
                                  (((s6 * 4 + lg) ^ (nl & 7)) << 4));
      acc[0][nt] = __builtin_amdgcn_mfma_f32_16x16x32_bf16(af0, b, acc[0][nt], 0, 0, 0);
      acc[1][nt] = __builtin_amdgcn_mfma_f32_16x16x32_bf16(af1, b, acc[1][nt], 0, 0, 0);
    }
  }

  // ---- epilogue: acc -> LDS bounce ([128][192] bf16 = 48 KB, reuse Wl) ----
  __syncthreads();
  u16* Cb = (u16*)Wl;
#pragma unroll
  for (int rt = 0; rt < 2; ++rt)
#pragma unroll
    for (int nt = 0; nt < 6; ++nt)
#pragma unroll
      for (int r = 0; r < 4; ++r) {
        int mloc = rg * 32 + rt * 16 + lg * 4 + r;  // D row = (lane>>4)*4 + reg
        Cb[mloc * 192 + cg * 96 + nt * 16 + l15] = f2bf(acc[rt][nt][r]);
      }
  __syncthreads();
  {
    u16* const bases[3] = {kws, qws, vws};
#pragma unroll
    for (int i = 0; i < 6; ++i) {
      int idx = tid + i * 512;           // 0..3071 = 128 rows x 24 granules
      int row = idx / 24, g = idx - row * 24;
      uint4 d = *(const uint4*)(Cb + row * 192 + g * 8);
      *(uint4*)(bases[g >> 3] + (m0 + row) * NH + (g & 7) * 8) = d;
    }
  }
}

// ---------------- kernel 2: fused causal attention per batch -----------------
__global__ __launch_bounds__(256) void attn_k(const u16* __restrict__ kws,
                                              const u16* __restrict__ qws,
                                              const u16* __restrict__ vws,
                                              float* __restrict__ out) {
  __shared__ u16 Klds[256 * 64];      // 32 KB, [s][h], swizzled
  __shared__ u16 VT[64 * 256];        // 32 KB, [h][s], swizzled
  const int b = blockIdx.x;
  const int tid = threadIdx.x, lane = tid & 63, w = tid >> 6;
  const int gl = lane >> 5, l31 = lane & 31;
  const u16* kb = kws + (size_t)b * NT * NH;
  const u16* qb = qws + (size_t)b * NT * NH;
  const u16* vb = vws + (size_t)b * NT * NH;

#pragma unroll
  for (int p = 0; p < 8; ++p) {
    int u = tid + p * 256;
    int row = u >> 3, c16 = u & 7;
    uint4 d = *(const uint4*)(kb + row * 64 + c16 * 8);
    *(uint4*)((char*)Klds + row * 128 + ((c16 * 16) ^ ((row & 7) << 4))) = d;
  }
#pragma unroll
  for (int p = 0; p < 8; ++p) {
    int u = tid + p * 256;
    int s = u >> 3, h0 = (u & 7) * 8;
    uint4 d = *(const uint4*)(vb + s * 64 + h0);
    u32 ww[4] = {d.x, d.y, d.z, d.w};
#pragma unroll
    for (int j = 0; j < 4; ++j) {
      int h = h0 + 2 * j;
      *(u16*)((char*)VT + h * 512 + ((s * 2) ^ ((h & 7) << 4))) = (u16)(ww[j] & 0xffffu);
      *(u16*)((char*)VT + (h + 1) * 512 + ((s * 2) ^ (((h + 1) & 7) << 4))) = (u16)(ww[j] >> 16);
    }
  }
  __syncthreads();

  const float cexp = 0.05103103630798287f * 1.4426950408889634f;  // C^-0.5 * log2(e)

#pragma unroll
  for (int pass = 0; pass < 2; ++pass) {
    const int qt = (pass == 0) ? w : 7 - w;
    const int t0 = qt * 32;

    bf16x8 bq[4];
#pragma unroll
    for (int kk = 0; kk < 4; ++kk)
      bq[kk] = *(const bf16x8*)(qb + (t0 + l31) * NH + kk * 16 + gl * 8);

    f32x16 sf[8];
#pragma unroll
    for (int f = 0; f < 8; ++f) {
      if (f <= qt) {
        f32x16 z = {};
        sf[f] = z;
#pragma unroll
        for (int kk = 0; kk < 4; ++kk) {
          int arow = f * 32 + l31;
          bf16x8 a = *(const bf16x8*)((const char*)Klds + arow * 128 +
                                      ((kk * 32 + gl * 16) ^ ((arow & 7) << 4)));
          sf[f] = __builtin_amdgcn_mfma_f32_32x32x16_bf16(a, bq[kk], sf[f], 0, 0, 0);
        }
      }
    }

    float mmax = -INFINITY;
#pragma unroll
    for (int f = 0; f < 8; ++f) {
      if (f < qt) {
#pragma unroll
        for (int r = 0; r < 16; ++r) mmax = fmaxf(mmax, sf[f][r]);
      } else if (f == qt) {
#pragma unroll
        for (int r = 0; r < 16; ++r) {
          int sloc = (r & 3) + 8 * (r >> 2) + 4 * gl;
          float v = (sloc <= l31) ? sf[f][r] : -INFINITY;
          mmax = fmaxf(mmax, v);
        }
      }
    }
    mmax = fmaxf(mmax, __shfl_xor(mmax, 32));

    float lsum = 0.0f;
#pragma unroll
    for (int f = 0; f < 8; ++f) {
      if (f <= qt) {
#pragma unroll
        for (int r = 0; r < 16; ++r) {
          float e = exp2f((sf[f][r] - mmax) * cexp);
          if (f == qt) {
            int sloc = (r & 3) + 8 * (r >> 2) + 4 * gl;
            e = (sloc <= l31) ? e : 0.0f;
          }
          sf[f][r] = e;
          lsum += e;
        }
      }
    }
    lsum += __shfl_xor(lsum, 32);

    f32x16 ao0 = {}, ao1 = {};
#pragma unroll
    for (int f = 0; f < 8; ++f) {
      if (f <= qt) {
        u32 a0 = pkbf(sf[f][0], sf[f][1]);
        u32 a1 = pkbf(sf[f][2], sf[f][3]);
        u32 b0 = pkbf(sf[f][4], sf[f][5]);
        u32 b1 = pkbf(sf[f][6], sf[f][7]);
        pl32swap(a0, b0);
        pl32swap(a1, b1);
        u32x4 te = {a0, a1, b0, b1};
        bf16x8 bpe = __builtin_bit_cast(bf16x8, te);
        u32 c0 = pkbf(sf[f][8], sf[f][9]);
        u32 c1 = pkbf(sf[f][10], sf[f][11]);
        u32 d0 = pkbf(sf[f][12], sf[f][13]);
        u32 d1 = pkbf(sf[f][14], sf[f][15]);
        pl32swap(c0, d0);
        pl32swap(c1, d1);
        u32x4 to = {c0, c1, d0, d1};
        bf16x8 bpo = __builtin_bit_cast(bf16x8, to);

        int se = (f * 32 + gl * 8) * 2;
        int so = se + 32;
        bf16x8 av0e = *(const bf16x8*)((char*)VT + l31 * 512 + (se ^ ((l31 & 7) << 4)));
        bf16x8 av1e = *(const bf16x8*)((char*)VT + (32 + l31) * 512 + (se ^ ((l31 & 7) << 4)));
        ao0 = __builtin_amdgcn_mfma_f32_32x32x16_bf16(av0e, bpe, ao0, 0, 0, 0);
        ao1 = __builtin_amdgcn_mfma_f32_32x32x16_bf16(av1e, bpe, ao1, 0, 0, 0);
        bf16x8 av0o = *(const bf16x8*)((char*)VT + l31 * 512 + (so ^ ((l31 & 7) << 4)));
        bf16x8 av1o = *(const bf16x8*)((char*)VT + (32 + l31) * 512 + (so ^ ((l31 & 7) << 4)));
        ao0 = __builtin_amdgcn_mfma_f32_32x32x16_bf16(av0o, bpo, ao0, 0, 0, 0);
        ao1 = __builtin_amdgcn_mfma_f32_32x32x16_bf16(av1o, bpo, ao1, 0, 0, 0);
      }
    }

    float rl = 1.0f / lsum;
    float* ob = out + ((size_t)b * NT + t0 + l31) * NH;
#pragma unroll
    for (int g = 0; g < 4; ++g) {
      float4 v0 = make_float4(ao0[4 * g + 0] * rl, ao0[4 * g + 1] * rl,
                              ao0[4 * g + 2] * rl, ao0[4 * g + 3] * rl);
      float4 v1 = make_float4(ao1[4 * g + 0] * rl, ao1[4 * g + 1] * rl,
                              ao1[4 * g + 2] * rl, ao1[4 * g + 3] * rl);
      *(float4*)(ob + 8 * g + 4 * gl) = v0;
      *(float4*)(ob + 32 + 8 * g + 4 * gl) = v1;
    }
  }
}

// ---------------- launch -----------------------------------------------------
extern "C" void kernel_launch(void* const* d_in, const int* in_sizes, int n_in,
                              void* d_out, int out_size, void* d_ws, size_t ws_size,
                              hipStream_t stream) {
  const float* x = (const float*)d_in[0];
  const float* wk = (const float*)d_in[1];
  const float* wq = (const float*)d_in[2];
  const float* wv = (const float*)d_in[3];
  float* out = (float*)d_out;

  char* ws = (char*)d_ws;
  u16* wb = (u16*)ws;                                   // 147456 B
  u16* kws = (u16*)(ws + (1 << 20));                    // 16 MB each
  u16* qws = kws + (size_t)NB * NT * NH;
  u16* vws = qws + (size_t)NB * NT * NH;

  wconv_k<<<288, 256, 0, stream>>>(wk, wq, wv, wb);
  qkv_gemm<<<1024, 512, 0, stream>>>(x, wb, kws, qws, vws);
  attn_k<<<512, 256, 0, stream>>>(kws, qws, vws, out);
}

// Round 8
// 69.140 us; speedup vs baseline: 1.7576x; 1.7348x over previous
//
#include <hip/hip_runtime.h>

#define NB 512
#define NT 256
#define NC 384
#define NH 64

typedef __bf16 bf16x8 __attribute__((ext_vector_type(8)));
typedef float f32x4 __attribute__((ext_vector_type(4)));
typedef float f32x16 __attribute__((ext_vector_type(16)));
typedef unsigned int u32;
typedef unsigned int u32x4 __attribute__((ext_vector_type(4)));
typedef unsigned short u16;

__device__ __forceinline__ u16 f2bf(float x) {
  u32 u = __builtin_bit_cast(u32, x);
  u32 r = (u + 0x7fffu + ((u >> 16) & 1u)) >> 16;  // RNE
  return (u16)r;
}
__device__ __forceinline__ u32 pkbf(float lo, float hi) {
  u32 r;
  asm("v_cvt_pk_bf16_f32 %0, %1, %2" : "=v"(r) : "v"(lo), "v"(hi));
  return r;
}
__device__ __forceinline__ void pl32swap(u32& a, u32& b) {
  asm volatile("v_permlane32_swap_b32 %0, %1" : "+v"(a), "+v"(b));
}

// ---------------- kernel 0: W (3x[64][384] f32) -> combined [192][384] bf16 ----
__global__ __launch_bounds__(256) void wconv_k(const float* __restrict__ wk,
                                               const float* __restrict__ wq,
                                               const float* __restrict__ wv,
                                               u16* __restrict__ wb) {
  int i = blockIdx.x * 256 + threadIdx.x;
  if (i >= 192 * NC) return;
  int row = i / NC, col = i - row * NC;
  const float* s = (row < 64) ? wk : ((row < 128) ? wq : wv);
  wb[i] = f2bf(s[(row & 63) * NC + col]);
}

// ---------------- fused kernel: QKV GEMM (R4-exact) + attention --------------
// One block = one batch (256 rows), 1024 thr = 16 waves, grid 512.
// Phase 1: R4's proven barrier-free GEMM (W 147 KB resident, x reg-prefetch).
// Phase 2: acc -> K/VT/Q in LDS (overlay W); attention with wave-pair f-split:
//   wave w<8: tile w, frags [0,min(qt+1,4)); wave w>=8: tile 15-w, frags [4,qt+1).
//   Joint softmax m/l and partial-PV combined via small LDS buffers.
__global__ __launch_bounds__(1024) void fused_k(const float* __restrict__ x,
                                                const u16* __restrict__ wb,
                                                float* __restrict__ out) {
  __shared__ __align__(16) char smem[147456];
  u16* Wl = (u16*)smem;
  const int tid = threadIdx.x;
  const int lane = tid & 63, w = tid >> 6;
  const int l15 = lane & 15, lg = lane >> 4;   // GEMM indexing
  const int l31 = lane & 31, gl = lane >> 5;   // attn indexing
  const size_t m0 = (size_t)blockIdx.x * 256;

  // ---- phase 1: GEMM (R4-exact) ----
  const float* xp = x + (m0 + (size_t)(w * 16 + l15)) * NC + lg * 8;
  float4 pX[4], pY[4];
#pragma unroll
  for (int s = 0; s < 4; ++s) {
    pX[s] = *(const float4*)(xp + s * 32);
    pY[s] = *(const float4*)(xp + s * 32 + 4);
  }
#pragma unroll
  for (int i = 0; i < 9; ++i) {
    int idx = tid + i * 1024;          // 0..9215
    int row = idx / 48, gs = idx - row * 48;
    int gk = gs ^ (row & 7);
    uint4 d = *(const uint4*)(wb + row * NC + gk * 8);
    *(uint4*)((char*)Wl + row * 768 + gs * 16) = d;
  }
  __syncthreads();

  f32x4 acc[12];
#pragma unroll
  for (int nt = 0; nt < 12; ++nt) {
    f32x4 z = {};
    acc[nt] = z;
  }
#pragma unroll
  for (int kk = 0; kk < 12; ++kk) {
    const int st = kk & 3;
    u32x4 av = {pkbf(pX[st].x, pX[st].y), pkbf(pX[st].z, pX[st].w),
                pkbf(pY[st].x, pY[st].y), pkbf(pY[st].z, pY[st].w)};
    bf16x8 afrag = __builtin_bit_cast(bf16x8, av);
    if (kk < 8) {
      pX[st] = *(const float4*)(xp + (kk + 4) * 32);
      pY[st] = *(const float4*)(xp + (kk + 4) * 32 + 4);
    }
#pragma unroll
    for (int nt = 0; nt < 12; ++nt) {
      int brow = nt * 16 + l15;
      bf16x8 b = *(const bf16x8*)((const char*)Wl + brow * 768 +
                                  (((kk * 4 + lg) ^ (brow & 7)) << 4));
      acc[nt] = __builtin_amdgcn_mfma_f32_16x16x32_bf16(afrag, b, acc[nt], 0, 0, 0);
    }
  }
  __syncthreads();  // Wl dead; reuse LDS

  // ---- phase 2a: acc -> Klds/Qlds/VT (attn layouts, swizzled) ----
  // regions: K @0 (32K), VT @32K (32K), Q @64K (32K), m/l @96K (4K), ao @100K (32K)
  char* Kb = smem;
  char* Vb = smem + 32768;
  char* Qb = smem + 65536;
  float* mlb = (float*)(smem + 98304);    // m: [8][2][32]; l: +512 floats
  float* aob = (float*)(smem + 102400);   // [8][32][32] f32
#pragma unroll
  for (int nt = 0; nt < 12; ++nt) {
#pragma unroll
    for (int r = 0; r < 4; ++r) {
      int s = w * 16 + lg * 4 + r;        // row within batch (0..255)
      u16 v = f2bf(acc[nt][r]);
      if (nt < 4) {
        int h = nt * 16 + l15;
        *(u16*)(Kb + s * 128 + ((h * 2) ^ ((s & 7) << 4))) = v;
      } else if (nt < 8) {
        int h = (nt - 4) * 16 + l15;
        *(u16*)(Qb + s * 128 + ((h * 2) ^ ((s & 7) << 4))) = v;
      } else {
        int h = (nt - 8) * 16 + l15;
        *(u16*)(Vb + h * 512 + ((s * 2) ^ ((h & 7) << 4))) = v;
      }
    }
  }
  __syncthreads();

  // ---- phase 2b: attention ----
  const float cexp = 0.05103103630798287f * 1.4426950408889634f;  // C^-0.5*log2(e)
  const bool lo = (w < 8);
  const int qt = lo ? w : (15 - w);
  const int t0 = qt * 32;
  const int f1 = lo ? ((qt + 1 < 4) ? qt + 1 : 4) : (qt + 1);  // f in [f0,f1)
  const int f0 = lo ? 0 : 4;
  const int tq = t0 + l31;

  // QK^T partials (sf[fi] for f = f0+fi)
  f32x16 sf[4];
#pragma unroll
  for (int fi = 0; fi < 4; ++fi) {
    int f = f0 + fi;
    if (f < f1) {
      f32x16 z = {};
      sf[fi] = z;
#pragma unroll
      for (int kk = 0; kk < 4; ++kk) {
        int arow = f * 32 + l31;
        bf16x8 a = *(const bf16x8*)(Kb + arow * 128 +
                                    ((kk * 32 + gl * 16) ^ ((arow & 7) << 4)));
        bf16x8 bq = *(const bf16x8*)(Qb + tq * 128 +
                                     ((kk * 32 + gl * 16) ^ ((tq & 7) << 4)));
        sf[fi] = __builtin_amdgcn_mfma_f32_32x32x16_bf16(a, bq, sf[fi], 0, 0, 0);
      }
    }
  }

  // partial row max
  float pm = -INFINITY;
#pragma unroll
  for (int fi = 0; fi < 4; ++fi) {
    int f = f0 + fi;
    if (f < f1) {
      if (f < qt) {
#pragma unroll
        for (int r = 0; r < 16; ++r) pm = fmaxf(pm, sf[fi][r]);
      } else {
#pragma unroll
        for (int r = 0; r < 16; ++r) {
          int sloc = (r & 3) + 8 * (r >> 2) + 4 * gl;
          pm = fmaxf(pm, (sloc <= l31) ? sf[fi][r] : -INFINITY);
        }
      }
    }
  }
  pm = fmaxf(pm, __shfl_xor(pm, 32));
  if (gl == 0) mlb[(qt * 2 + (lo ? 0 : 1)) * 32 + l31] = pm;
  __syncthreads();
  float m = fmaxf(pm, mlb[(qt * 2 + (lo ? 1 : 0)) * 32 + l31]);

  // exp + partial sum
  float ls = 0.0f;
#pragma unroll
  for (int fi = 0; fi < 4; ++fi) {
    int f = f0 + fi;
    if (f < f1) {
#pragma unroll
      for (int r = 0; r < 16; ++r) {
        float e = exp2f((sf[fi][r] - m) * cexp);
        if (f == qt) {
          int sloc = (r & 3) + 8 * (r >> 2) + 4 * gl;
          e = (sloc <= l31) ? e : 0.0f;
        }
        sf[fi][r] = e;
        ls += e;
      }
    }
  }
  ls += __shfl_xor(ls, 32);
  if (gl == 0) mlb[512 + (qt * 2 + (lo ? 0 : 1)) * 32 + l31] = ls;
  __syncthreads();
  float lsum = ls + mlb[512 + (qt * 2 + (lo ? 1 : 0)) * 32 + l31];

  // PV partials (T12 in-register P -> B-frags)
  f32x16 ao0 = {}, ao1 = {};
#pragma unroll
  for (int fi = 0; fi < 4; ++fi) {
    int f = f0 + fi;
    if (f < f1) {
      u32 a0 = pkbf(sf[fi][0], sf[fi][1]);
      u32 a1 = pkbf(sf[fi][2], sf[fi][3]);
      u32 b0 = pkbf(sf[fi][4], sf[fi][5]);
      u32 b1 = pkbf(sf[fi][6], sf[fi][7]);
      pl32swap(a0, b0);
      pl32swap(a1, b1);
      u32x4 te = {a0, a1, b0, b1};
      bf16x8 bpe = __builtin_bit_cast(bf16x8, te);
      u32 c0 = pkbf(sf[fi][8], sf[fi][9]);
      u32 c1 = pkbf(sf[fi][10], sf[fi][11]);
      u32 d0 = pkbf(sf[fi][12], sf[fi][13]);
      u32 d1 = pkbf(sf[fi][14], sf[fi][15]);
      pl32swap(c0, d0);
      pl32swap(c1, d1);
      u32x4 to = {c0, c1, d0, d1};
      bf16x8 bpo = __builtin_bit_cast(bf16x8, to);

      int se = (f * 32 + gl * 8) * 2;
      int so = se + 32;
      bf16x8 av0e = *(const bf16x8*)(Vb + l31 * 512 + (se ^ ((l31 & 7) << 4)));
      bf16x8 av1e = *(const bf16x8*)(Vb + (32 + l31) * 512 + (se ^ ((l31 & 7) << 4)));
      ao0 = __builtin_amdgcn_mfma_f32_32x32x16_bf16(av0e, bpe, ao0, 0, 0, 0);
      ao1 = __builtin_amdgcn_mfma_f32_32x32x16_bf16(av1e, bpe, ao1, 0, 0, 0);
      bf16x8 av0o = *(const bf16x8*)(Vb + l31 * 512 + (so ^ ((l31 & 7) << 4)));
      bf16x8 av1o = *(const bf16x8*)(Vb + (32 + l31) * 512 + (so ^ ((l31 & 7) << 4)));
      ao0 = __builtin_amdgcn_mfma_f32_32x32x16_bf16(av0o, bpo, ao0, 0, 0, 0);
      ao1 = __builtin_amdgcn_mfma_f32_32x32x16_bf16(av1o, bpo, ao1, 0, 0, 0);
    }
  }

  // combine partial ao across the wave pair (hi writes, lo adds)
  if (!lo) {
#pragma unroll
    for (int r = 0; r < 16; ++r) {
      int hrow = (r & 3) + 8 * (r >> 2) + 4 * gl;
      aob[qt * 1024 + hrow * 32 + l31] = ao0[r];
    }
  }
  __syncthreads();
  if (lo) {
#pragma unroll
    for (int r = 0; r < 16; ++r) {
      int hrow = (r & 3) + 8 * (r >> 2) + 4 * gl;
      ao0[r] += aob[qt * 1024 + hrow * 32 + l31];
    }
  }
  __syncthreads();
  if (!lo) {
#pragma unroll
    for (int r = 0; r < 16; ++r) {
      int hrow = (r & 3) + 8 * (r >> 2) + 4 * gl;
      aob[qt * 1024 + hrow * 32 + l31] = ao1[r];
    }
  }
  __syncthreads();
  if (lo) {
    float rl = 1.0f / lsum;
    float* ob = out + (m0 + t0 + l31) * NH;
#pragma unroll
    for (int g = 0; g < 4; ++g) {
      float4 v0, v1;
#pragma unroll
      for (int j = 0; j < 4; ++j) {
        int r = 4 * g + j;
        int hrow = (r & 3) + 8 * (r >> 2) + 4 * gl;
        float a1c = ao1[r] + aob[qt * 1024 + hrow * 32 + l31];
        ((float*)&v0)[j] = ao0[r] * rl;
        ((float*)&v1)[j] = a1c * rl;
      }
      *(float4*)(ob + 8 * g + 4 * gl) = v0;
      *(float4*)(ob + 32 + 8 * g + 4 * gl) = v1;
    }
  }
}

// ---------------- launch -----------------------------------------------------
extern "C" void kernel_launch(void* const* d_in, const int* in_sizes, int n_in,
                              void* d_out, int out_size, void* d_ws, size_t ws_size,
                              hipStream_t stream) {
  const float* x = (const float*)d_in[0];
  const float* wk = (const float*)d_in[1];
  const float* wq = (const float*)d_in[2];
  const float* wv = (const float*)d_in[3];
  float* out = (float*)d_out;

  u16* wb = (u16*)d_ws;  // 147456 B

  wconv_k<<<288, 256, 0, stream>>>(wk, wq, wv, wb);
  fused_k<<<512, 1024, 0, stream>>>(x, wb, out);
}